// Round 3
// baseline (253.788 us; speedup 1.0000x reference)
//
#include <hip/hip_runtime.h>

typedef short bf16x8 __attribute__((ext_vector_type(8)));
typedef float f32x4 __attribute__((ext_vector_type(4)));

#define K_CODES 1024
#define D_DIM   256
#define HWSZ    1024
#define OUT_ELEMS 16777216

__device__ __forceinline__ unsigned short f2bf(float x) {
    unsigned int u = __float_as_uint(x);
    u += 0x7FFFu + ((u >> 16) & 1u);   // RNE
    return (unsigned short)(u >> 16);
}

__device__ __forceinline__ unsigned long long pack4bf(float a, float b, float c, float d) {
    unsigned long long u0 = f2bf(a), u1 = f2bf(b), u2 = f2bf(c), u3 = f2bf(d);
    return u0 | (u1 << 16) | (u2 << 32) | (u3 << 48);
}

// -------- prep: ||e_k||^2 per code + zero the loss accumulator --------
__global__ void enorm_kernel(const float* __restrict__ emb,
                             float* __restrict__ eNorm,
                             float* __restrict__ lossAcc) {
    int k = blockIdx.x;          // 1024 blocks
    int lane = threadIdx.x;      // 64 threads
    const float4* row = reinterpret_cast<const float4*>(emb + k * D_DIM);
    float4 v = row[lane];
    float s = v.x * v.x + v.y * v.y + v.z * v.z + v.w * v.w;
    #pragma unroll
    for (int off = 32; off > 0; off >>= 1) s += __shfl_down(s, off, 64);
    if (lane == 0) eNorm[k] = s;
    if (k == 0 && lane == 0) *lossAcc = 0.0f;
}

// -------- prep: pack E into B-fragment order with permuted k-mapping --------
// lane l elem e  <-  E[ctile*16 + (l&15)][dc*32 + (e>>2)*16 + (l>>4)*4 + (e&3)]
__global__ void pack_e(const float* __restrict__ emb, bf16x8* __restrict__ Ep) {
    int fid = blockIdx.x;        // 512 = ctile*8 + dc
    int l = threadIdx.x;         // 64
    int ctile = fid >> 3, dc = fid & 7;
    const float* src = emb + (ctile * 16 + (l & 15)) * D_DIM + dc * 32 + ((l >> 4) << 2);
    float4 f0 = *reinterpret_cast<const float4*>(src);        // e = 0..3
    float4 f1 = *reinterpret_cast<const float4*>(src + 16);   // e = 4..7
    bf16x8 v;
    v[0] = (short)f2bf(f0.x); v[1] = (short)f2bf(f0.y);
    v[2] = (short)f2bf(f0.z); v[3] = (short)f2bf(f0.w);
    v[4] = (short)f2bf(f1.x); v[5] = (short)f2bf(f1.y);
    v[6] = (short)f2bf(f1.z); v[7] = (short)f2bf(f1.w);
    Ep[fid * 64 + l] = v;
}

// -------- fused main: stage+convert + MFMA + argmin + gather + out + loss --------
// 512 blocks x 256 thr (4 waves, 2x2). Block tile 128 rows x 1024 codes.
__launch_bounds__(256, 2)
__global__ void vq_main(const float* __restrict__ lat, const bf16x8* __restrict__ Ep,
                        const float* __restrict__ eNorm, const float* __restrict__ emb,
                        float* __restrict__ out, float* __restrict__ lossAcc) {
    __shared__ unsigned long long Xs64[8192];   // 64 KB: [q (d-quad 0..63)][r 0..127]
    __shared__ float eNormS[1024];
    __shared__ float wbV[256];                  // [row][wc]
    __shared__ int   wbI[256];
    __shared__ int   idxs[128];

    const int t = threadIdx.x;
    const int lane = t & 63;
    const int w = t >> 6;
    const int wr = w >> 1, wc = w & 1;
    const int l15 = lane & 15, lhi = lane >> 4;
    const int R0 = blockIdx.x * 128;
    const float* latB = lat + (R0 >> 10) * (D_DIM * HWSZ) + (R0 & 1023);

    #pragma unroll
    for (int p = 0; p < 4; ++p) eNormS[p * 256 + t] = eNorm[p * 256 + t];

    // ---- stage X tile: global (d-major) -> bf16 LDS [q][r], accumulate ||x||^2 ----
    float xsq = 0.0f;
    for (int qi = 0; qi < 16; ++qi) {
        const int q = w * 16 + qi;
        #pragma unroll
        for (int rh = 0; rh < 2; ++rh) {
            const int r = rh * 64 + lane;
            const float* src = latB + (q * 4) * HWSZ + r;
            float v0 = src[0];
            float v1 = src[HWSZ];
            float v2 = src[2 * HWSZ];
            float v3 = src[3 * HWSZ];
            xsq += v0 * v0 + v1 * v1 + v2 * v2 + v3 * v3;
            Xs64[q * 128 + r] = pack4bf(v0, v1, v2, v3);
        }
    }
    #pragma unroll
    for (int off = 32; off > 0; off >>= 1) xsq += __shfl_down(xsq, off, 64);
    if (lane == 0) atomicAdd(lossAcc, xsq);
    __syncthreads();

    // ---- MFMA distance + running argmin ----
    float best[4][4];
    int   bidx[4][4];
    #pragma unroll
    for (int i = 0; i < 4; ++i)
        #pragma unroll
        for (int rs = 0; rs < 4; ++rs) { best[i][rs] = 3.4e38f; bidx[i][rs] = 0; }

    for (int ct = 0; ct < 8; ++ct) {
        f32x4 acc[4][4];
        #pragma unroll
        for (int i = 0; i < 4; ++i)
            #pragma unroll
            for (int j = 0; j < 4; ++j) acc[i][j] = (f32x4){0.f, 0.f, 0.f, 0.f};

        #pragma unroll
        for (int dc = 0; dc < 8; ++dc) {
            bf16x8 bfr[4], afr[4];
            #pragma unroll
            for (int j = 0; j < 4; ++j)
                bfr[j] = Ep[((ct * 8 + wc * 4 + j) * 8 + dc) * 64 + lane];
            #pragma unroll
            for (int i = 0; i < 4; ++i) {
                const int r = (wr * 4 + i) * 16 + l15;
                union { unsigned long long u[2]; bf16x8 v; } fr;
                fr.u[0] = Xs64[(dc * 8 + lhi) * 128 + r];
                fr.u[1] = Xs64[(dc * 8 + 4 + lhi) * 128 + r];
                afr[i] = fr.v;
            }
            #pragma unroll
            for (int i = 0; i < 4; ++i)
                #pragma unroll
                for (int j = 0; j < 4; ++j)
                    acc[i][j] = __builtin_amdgcn_mfma_f32_16x16x32_bf16(afr[i], bfr[j], acc[i][j], 0, 0, 0);
        }
        #pragma unroll
        for (int j = 0; j < 4; ++j) {
            const int k = ct * 128 + wc * 64 + j * 16 + l15;
            const float en = eNormS[k];
            #pragma unroll
            for (int i = 0; i < 4; ++i)
                #pragma unroll
                for (int rs = 0; rs < 4; ++rs) {
                    float s = en - 2.0f * acc[i][j][rs];
                    if (s < best[i][rs]) { best[i][rs] = s; bidx[i][rs] = k; }
                }
        }
    }

    // ---- argmin reduce: shfl_xor over the 16 l15 lanes, then across wc ----
    #pragma unroll
    for (int i = 0; i < 4; ++i)
        #pragma unroll
        for (int rs = 0; rs < 4; ++rs) {
            float v = best[i][rs]; int ix = bidx[i][rs];
            #pragma unroll
            for (int m = 1; m <= 8; m <<= 1) {
                float ov = __shfl_xor(v, m, 64);
                int   oi = __shfl_xor(ix, m, 64);
                if (ov < v || (ov == v && oi < ix)) { v = ov; ix = oi; }
            }
            if (l15 == 0) {
                const int row = wr * 64 + i * 16 + lhi * 4 + rs;
                wbV[row * 2 + wc] = v;
                wbI[row * 2 + wc] = ix;
            }
        }
    __syncthreads();

    if (t < 128) {
        float v0 = wbV[t * 2], v1 = wbV[t * 2 + 1];
        int   i0 = wbI[t * 2], i1 = wbI[t * 2 + 1];
        float bv; int bi;
        if (v1 < v0 || (v1 == v0 && i1 < i0)) { bv = v1; bi = i1; }
        else                                  { bv = v0; bi = i0; }
        idxs[t] = bi;
        float lsum = bv;   // eNorm[bi] - 2*dot : the rest of the loss
        #pragma unroll
        for (int off = 32; off > 0; off >>= 1) lsum += __shfl_down(lsum, off, 64);
        if (lane == 0) atomicAdd(lossAcc, lsum);
    }
    __syncthreads();   // idxs visible; Xs64 dead -> reuse as Qs

    // ---- epilogue: gather emb rows -> LDS transpose -> coalesced out ----
    float* Qs = reinterpret_cast<float*>(Xs64);   // 32*257 floats = 32.9 KB
    float* outB = out + (R0 >> 10) * (D_DIM * HWSZ) + (R0 & 1023);
    for (int rc = 0; rc < 4; ++rc) {
        const int r0 = rc * 32;
        #pragma unroll
        for (int p = 0; p < 8; ++p) {
            const int slot = p * 256 + t;
            const int rloc = slot >> 6, f4 = slot & 63;
            const float4 qv = *reinterpret_cast<const float4*>(emb + idxs[r0 + rloc] * D_DIM + f4 * 4);
            float* dst = &Qs[rloc * 257 + f4 * 4];
            dst[0] = qv.x; dst[1] = qv.y; dst[2] = qv.z; dst[3] = qv.w;
        }
        __syncthreads();
        {
            const int rr = (t & 15) * 2, dg = t >> 4;   // 16 d-groups x 16 row-pairs
            #pragma unroll
            for (int p = 0; p < 16; ++p) {
                const int d = dg * 16 + p;
                float2 v = { Qs[rr * 257 + d], Qs[(rr + 1) * 257 + d] };
                *reinterpret_cast<float2*>(&outB[d * HWSZ + r0 + rr]) = v;
            }
        }
        __syncthreads();
    }
}

// -------- finalize: write the two loss scalars --------
__global__ void finalize_kernel(const float* __restrict__ lossAcc,
                                float* __restrict__ out_tail) {
    float mse = *lossAcc * (1.0f / 16777216.0f);
    out_tail[0] = mse;          // embedding_loss
    out_tail[1] = 0.25f * mse;  // BETA * commitment_loss
}

extern "C" void kernel_launch(void* const* d_in, const int* in_sizes, int n_in,
                              void* d_out, int out_size, void* d_ws, size_t ws_size,
                              hipStream_t stream) {
    (void)in_sizes; (void)n_in; (void)out_size; (void)ws_size;
    const float* lat = (const float*)d_in[0];
    const float* emb = (const float*)d_in[1];
    float* out = (float*)d_out;

    char* ws = (char*)d_ws;
    bf16x8* Ep     = (bf16x8*)ws;                       // 512 KB
    float*  eNorm  = (float*)(ws + (512u << 10));       // 4 KB
    float*  lossAcc = eNorm + K_CODES;                  // 4 B

    hipLaunchKernelGGL(enorm_kernel, dim3(K_CODES), dim3(64), 0, stream,
                       emb, eNorm, lossAcc);
    hipLaunchKernelGGL(pack_e, dim3(512), dim3(64), 0, stream, emb, Ep);
    hipLaunchKernelGGL(vq_main, dim3(512), dim3(256), 0, stream,
                       lat, Ep, eNorm, emb, out, lossAcc);
    hipLaunchKernelGGL(finalize_kernel, dim3(1), dim3(1), 0, stream,
                       lossAcc, out + OUT_ELEMS);
}